// Round 16
// baseline (540.198 us; speedup 1.0000x reference)
//
#include <hip/hip_runtime.h>
#include <hip/hip_bf16.h>

#define MM 8192
#define NN 11008
#define KK 4096
#define PKW 2048    // packed int32 words per output row

#define BM 256
#define BN 256
#define BKI 128                 // K per tile (i8)
#define NTI (KK / BKI)          // 32 K-tiles
#define NBM (MM / BM)           // 32
#define NBN (NN / BN)           // 43

typedef __attribute__((ext_vector_type(4)))  float f32x4;
typedef __attribute__((ext_vector_type(4)))  int   i32x4;
typedef __attribute__((ext_vector_type(16))) int   i32x16;
typedef __attribute__((ext_vector_type(8)))  short s16x8;
typedef __attribute__((ext_vector_type(4)))  short s16x4;

typedef __attribute__((address_space(3))) unsigned char        lds_u8;
typedef const __attribute__((address_space(1))) unsigned char  glb_u8;

static __device__ __forceinline__ unsigned short f2bf(float f) {
  union { float f; unsigned int u; } v; v.f = f;
  unsigned int u = v.u;
  u += 0x7fffu + ((u >> 16) & 1u);   // RNE
  return (unsigned short)(u >> 16);
}

// ---------------- workspace layout (PLANE-MAJOR per 256-row panel, 128-K block) ----
// ws: [panel][kb 0..31][plane 0..7][row 0..255][16B]; offset =
//   panel*1048576 + kb*32768 + p*4096 + r*16.
// A staged to LDS as one contiguous 32 KB chunk; B read DIRECT to registers
// (each half-wave's fragment = 512 contiguous bytes -> coalesced dwordx4).

// ---------------- quantize x: per-row absmax -> i8, plane-major ----------------

__global__ __launch_bounds__(256) void int4lin_quant_x(
    const float* __restrict__ X, signed char* __restrict__ O, float* __restrict__ xs)
{
  const int row  = blockIdx.x;
  const int t    = threadIdx.x;
  const int lane = t & 63;
  const int wave = t >> 6;
  const float* xr = X + (size_t)row * KK;

  f32x4 v[4];
  float mx = 0.0f;
#pragma unroll
  for (int j = 0; j < 4; ++j) {
    v[j] = *(const f32x4*)(xr + t * 16 + j * 4);
#pragma unroll
    for (int e = 0; e < 4; ++e) mx = fmaxf(mx, fabsf(v[j][e]));
  }
#pragma unroll
  for (int off = 32; off; off >>= 1) mx = fmaxf(mx, __shfl_xor(mx, off));
  __shared__ float red[4];
  if (lane == 0) red[wave] = mx;
  __syncthreads();
  mx = fmaxf(fmaxf(red[0], red[1]), fmaxf(red[2], red[3]));
  mx = fmaxf(mx, 1e-30f);
  const float rs = 127.0f / mx;
  if (t == 0) xs[row] = mx / 127.0f;

  i32x4 o;
#pragma unroll
  for (int w = 0; w < 4; ++w) {
    int acc = 0;
#pragma unroll
    for (int e = 0; e < 4; ++e) {
      int q = __float2int_rn(v[w][e] * rs);
      q = max(-127, min(127, q));
      acc |= (q & 0xff) << (8 * e);
    }
    o[w] = acc;
  }
  signed char* dst = O + (size_t)(row >> 8) * 1048576
                       + (size_t)(t >> 3) * 32768 + (size_t)(t & 7) * 4096
                       + (size_t)(row & 255) * 16;
  *(i32x4*)dst = o;
}

// ---------------- quantize w: nibbles -> i8 q in [-7,8], plane-major ----------------

__global__ void int4lin_quant_w(const int* __restrict__ P, signed char* __restrict__ O) {
  const int ntot = NN * 256;       // 16-byte output groups
  int i = blockIdx.x * blockDim.x + threadIdx.x;
  const int stride = gridDim.x * blockDim.x;
  for (; i < ntot; i += stride) {
    const int row = i >> 8;
    const int gr  = i & 255;
    const int* src = P + (size_t)row * PKW + gr * 8;   // 8 words -> 16 i8
    i32x4 va = *(const i32x4*)src;
    i32x4 vb = *(const i32x4*)(src + 4);
    i32x4 o;
#pragma unroll
    for (int h = 0; h < 2; ++h) {
      i32x4 w = h ? vb : va;
#pragma unroll
      for (int p = 0; p < 2; ++p) {
        const int b0 = w[2 * p], b1 = w[2 * p + 1];
        const int q0 = (b0 & 15) - 7, q1 = ((b0 >> 4) & 15) - 7;
        const int q2 = (b1 & 15) - 7, q3 = ((b1 >> 4) & 15) - 7;
        o[h * 2 + p] = (q0 & 0xff) | ((q1 & 0xff) << 8) | ((q2 & 0xff) << 16) | ((q3 & 0xff) << 24);
      }
    }
    signed char* dst = O + (size_t)(row >> 8) * 1048576
                         + (size_t)(gr >> 3) * 32768 + (size_t)(gr & 7) * 4096
                         + (size_t)(row & 255) * 16;
    *(i32x4*)dst = o;
  }
}

// ---------------- 256x256x128 i8 GEMM: A via LDS, B DIRECT to registers ----------
// R15 calibration: tile = MFMA 2342 + LDS(2304r+512w) + sync ~1250, serial.
// Change: B fragments bypass LDS entirely (plane-major ws -> coalesced
// global dwordx4, 512B/half-wave). LDS reads 24->16/wave, writes halved,
// LDS footprint 128->64 KB. B(t+1) double-buffered in regs; the existing
// boundary vmcnt(0) drains them (full-tile latency cover). Pair-unrolled
// tiles keep all B indices compile-time (no scratch). All else = R15.

__global__ __launch_bounds__(512, 2) void int4lin_gemm_i8(
    const signed char* __restrict__ Ai,   // plane-major panels
    const signed char* __restrict__ Bi,
    const float* __restrict__ xs,
    const float* __restrict__ scale,
    const float* __restrict__ bias,
    float* __restrict__ C)
{
  __shared__ signed char As[2][32768];   // 2 x 32 KiB (A only)

  const int tid  = threadIdx.x;
  const int lane = tid & 63;
  const int wave = tid >> 6;
  const int wm = wave >> 2;          // 0..1
  const int wn = wave & 3;           // 0..3

  // T1: bijective XCD swizzle (1376 = 8*172); consecutive swz share bm
  const int bid = blockIdx.x;
  const int swz = (bid & 7) * 172 + (bid >> 3);
  const int bm = swz / NBN;
  const int bn = swz - bm * NBN;

  const signed char* Abase = Ai + (size_t)bm * 1048576;
  const signed char* Bbase = Bi + (size_t)bn * 1048576;

  const int r5   = lane & 31;        // frag row/col within 32
  const int half = lane >> 5;        // k-half (16 i8) within instruction

  i32x16 acc[4][2] = {};             // [mf][nf]

  const int aoff0 = half * 4096 + (wm * 128 + r5) * 16;   // + ks*8192 + mf*512
  const int blane = half * 4096 + (wn * 64 + r5) * 16;    // + ks*8192 + nf*512

#define LDA(buf, mf, ks) (*(const i32x4*)(&As[buf][aoff0 + (ks) * 8192 + (mf) * 512]))

  auto stageA = [&](int buf, int kb) {
    const glb_u8* as = (const glb_u8*)(Abase + (size_t)kb * 32768 + tid * 16);
#pragma unroll
    for (int g = 0; g < 4; ++g)
      __builtin_amdgcn_global_load_lds(as + g * 8192,
          (lds_u8*)(&As[buf][g * 8192 + tid * 16]), 16, 0, 0);
  };

  auto loadB = [&](int kb, i32x4 (&br)[4][2]) {
    const signed char* p = Bbase + (size_t)kb * 32768 + blane;
#pragma unroll
    for (int ks = 0; ks < 4; ++ks)
#pragma unroll
      for (int nf = 0; nf < 2; ++nf)
        br[ks][nf] = *(const i32x4*)(p + ks * 8192 + nf * 512);
  };

  i32x4 b0[4][2], b1[4][2];

  // one tile: uses LDS[buf] + bc; prefetches A(t+1)->buf^1 and B(t+1)->bn
  auto tile = [&](int t, int buf, i32x4 (&bc)[4][2], i32x4 (&bn_)[4][2]) {
    if (t + 1 < NTI) {
      stageA(buf ^ 1, t + 1);
      loadB(t + 1, bn_);
    }
#pragma unroll
    for (int ks = 0; ks < 4; ++ks) {
      i32x4 a[4];
#pragma unroll
      for (int mf = 0; mf < 4; ++mf) a[mf] = LDA(buf, mf, ks);
      __builtin_amdgcn_s_setprio(1);
#pragma unroll
      for (int mf = 0; mf < 4; ++mf) {
        acc[mf][0] = __builtin_amdgcn_mfma_i32_32x32x32_i8(a[mf], bc[ks][0], acc[mf][0], 0, 0, 0);
        acc[mf][1] = __builtin_amdgcn_mfma_i32_32x32x32_i8(a[mf], bc[ks][1], acc[mf][1], 0, 0, 0);
      }
      __builtin_amdgcn_s_setprio(0);
    }
    if (t + 1 < NTI)
      asm volatile("s_waitcnt vmcnt(0)\n\ts_barrier" ::: "memory");
  };

  // -------- prologue: stage A0 -> buf0 (4 loads); load B0 -> regs (8 loads) ----
  stageA(0, 0);
  loadB(0, b0);
  asm volatile("s_waitcnt vmcnt(8)\n\ts_barrier" ::: "memory");   // A0 done; B0 via compiler waits

#pragma unroll 1
  for (int tt = 0; tt < NTI; tt += 2) {
    tile(tt,     0, b0, b1);
    tile(tt + 1, 1, b1, b0);
  }

  // epilogue: y = acc * xs[row] * scale[col] + bias[col], NON-TEMPORAL stores
  // C/D 32x32: col = lane&31, row = (reg&3) + 8*(reg>>2) + 4*half
  const size_t m0 = (size_t)bm * BM;
  const int colb = bn * BN + wn * 64 + r5;
#pragma unroll
  for (int mf = 0; mf < 4; ++mf) {
    const size_t rbase = m0 + wm * 128 + mf * 32 + 4 * half;
#pragma unroll
    for (int reg = 0; reg < 16; ++reg) {
      const size_t row = rbase + (reg & 3) + 8 * (reg >> 2);
      const float xsr = xs[row];
      float* cp = C + row * NN + colb;
#pragma unroll
      for (int nf = 0; nf < 2; ++nf) {
        const int col = colb + nf * 32;
        __builtin_nontemporal_store(
            (float)acc[mf][nf][reg] * xsr * scale[col] + bias[col], cp + nf * 32);
      }
    }
  }
#undef LDA
}

// ---------------- GEMM, inline-conversion bf16 fallback (no workspace needed) ----------------

__global__ __launch_bounds__(256) void int4lin_gemm_inline(
    const float* __restrict__ X,
    const int* __restrict__ P,
    const float* __restrict__ scale,
    const float* __restrict__ bias,
    float* __restrict__ C)
{
  __shared__ unsigned short As[128 * 64];
  __shared__ unsigned short Bs[128 * 64];

  const int tid  = threadIdx.x;
  const int lane = tid & 63;
  const int wave = tid >> 6;
  const int m0 = blockIdx.y * 128;
  const int n0 = blockIdx.x * 128;
  const int wr = (wave >> 1) * 64;
  const int wc = (wave & 1) * 64;

  f32x4 acc[4][4] = {};

  for (int kt = 0; kt < KK; kt += 64) {
#pragma unroll
    for (int i = 0; i < 8; ++i) {
      const int idx = i * 256 + tid;
      const int row = idx >> 4;
      const int c   = (idx & 15) << 2;
      f32x4 v = *(const f32x4*)(X + (size_t)(m0 + row) * KK + kt + c);
      s16x4 o;
      o[0] = (short)f2bf(v[0]); o[1] = (short)f2bf(v[1]);
      o[2] = (short)f2bf(v[2]); o[3] = (short)f2bf(v[3]);
      *(s16x4*)(As + row * 64 + (c ^ ((row & 7) << 3))) = o;
    }
#pragma unroll
    for (int i = 0; i < 4; ++i) {
      const int idx = i * 256 + tid;
      const int row = idx >> 3;
      const int c   = (idx & 7) << 3;
      i32x4 v = *(const i32x4*)(P + (size_t)(n0 + row) * PKW + ((kt + c) >> 1));
      s16x8 o;
#pragma unroll
      for (int j = 0; j < 4; ++j) {
        const int b = v[j];
        o[2 * j]     = (short)f2bf((float)((b & 15) - 7));
        o[2 * j + 1] = (short)f2bf((float)(((b >> 4) & 15) - 7));
      }
      *(s16x8*)(Bs + row * 64 + (c ^ ((row & 7) << 3))) = o;
    }
    __syncthreads();
#pragma unroll
    for (int kk = 0; kk < 2; ++kk) {
      const int rsel = lane & 15;
      const int ksel = ((((lane >> 4) << 3) + kk * 32)) ^ ((lane & 7) << 3);
      s16x8 af[4], bfr[4];
#pragma unroll
      for (int m = 0; m < 4; ++m)
        af[m] = *(const s16x8*)(As + (wr + m * 16 + rsel) * 64 + ksel);
#pragma unroll
      for (int n = 0; n < 4; ++n)
        bfr[n] = *(const s16x8*)(Bs + (wc + n * 16 + rsel) * 64 + ksel);
#pragma unroll
      for (int m = 0; m < 4; ++m)
#pragma unroll
        for (int n = 0; n < 4; ++n)
          acc[m][n] = __builtin_amdgcn_mfma_f32_16x16x32_bf16(af[m], bfr[n], acc[m][n], 0, 0, 0);
    }
    __syncthreads();
  }

  const int crow = wr + ((lane >> 4) << 2);
  const int ccol = wc + (lane & 15);
#pragma unroll
  for (int n = 0; n < 4; ++n) {
    const int gc = n0 + ccol + n * 16;
    const float sc = scale[gc];
    const float bi = bias[gc];
#pragma unroll
    for (int m = 0; m < 4; ++m) {
      float* cp = C + (size_t)(m0 + crow + m * 16) * NN + gc;
#pragma unroll
      for (int r = 0; r < 4; ++r)
        cp[(size_t)r * NN] = acc[m][n][r] * sc + bi;
    }
  }
}

// ---------------- launch ----------------

extern "C" void kernel_launch(void* const* d_in, const int* in_sizes, int n_in,
                              void* d_out, int out_size, void* d_ws, size_t ws_size,
                              hipStream_t stream) {
  const float* x      = (const float*)d_in[0];
  const int*   packed = (const int*)d_in[1];
  const float* scale  = (const float*)d_in[2];
  const float* bias   = (const float*)d_in[3];
  float* y = (float*)d_out;

  const size_t nXA = (size_t)MM * KK;                  // 32 MiB i8
  const size_t nWB = (size_t)NN * KK;                  // ~43 MiB i8
  const size_t nXS = (size_t)MM * sizeof(float);       // 32 KiB
  if (ws_size >= nXA + nWB + nXS) {
    signed char* xi = (signed char*)d_ws;
    signed char* wi = (signed char*)d_ws + nXA;
    float*       xsv = (float*)((char*)d_ws + nXA + nWB);
    int4lin_quant_x<<<MM, 256, 0, stream>>>(x, xi, xsv);
    int4lin_quant_w<<<2048, 256, 0, stream>>>(packed, wi);
    int4lin_gemm_i8<<<NBM * NBN, 512, 0, stream>>>(xi, wi, xsv, scale, bias, y);
    return;
  }
  dim3 grid(NN / 128, MM / 128);
  int4lin_gemm_inline<<<grid, 256, 0, stream>>>(x, packed, scale, bias, y);
}